// Round 1
// baseline (1615.263 us; speedup 1.0000x reference)
//
#include <hip/hip_runtime.h>

#define B_DIM 32
#define C_DIM 64
#define F_DIM 16384
#define O_DIM 128

// ---------------- Pass 1: transpose x (B,C,F) -> xt (B,F,C) ----------------
__global__ __launch_bounds__(256) void k_transpose(const float* __restrict__ x,
                                                   float* __restrict__ xt) {
    __shared__ float tile[64][65];
    const int b  = blockIdx.y;
    const int f0 = blockIdx.x * 64;
    const int t  = threadIdx.x;
    const int fl = t & 63;   // lane-varying
    const int q  = t >> 6;   // 0..3 (wave id)

    const float* xb = x + (size_t)b * C_DIM * F_DIM;
    #pragma unroll
    for (int i = 0; i < 16; ++i) {
        const int c = q + i * 4;
        tile[c][fl] = xb[(size_t)c * F_DIM + f0 + fl];   // coalesced read over f
    }
    __syncthreads();
    float* xtb = xt + ((size_t)b * F_DIM + f0) * C_DIM;
    #pragma unroll
    for (int i = 0; i < 16; ++i) {
        const int f = q + i * 4;
        xtb[(size_t)f * C_DIM + fl] = tile[fl][f];       // coalesced write over c
    }
}

// ------------- Pass 2: gather + beta + matmul, y -> d_out (B,O,F) -----------
template <bool TR>
__global__ __launch_bounds__(256) void k_compute(const float* __restrict__ xsrc,
                                                 const int*   __restrict__ adj,
                                                 const float* __restrict__ W,
                                                 const float* __restrict__ bias,
                                                 float*       __restrict__ y) {
    const int b = blockIdx.y;
    const int f = blockIdx.x * 256 + threadIdx.x;

    const int4 a = ((const int4*)adj)[(size_t)b * F_DIM + f];

    float tg[64];   // target row
    float bt[64];   // beta_f row

    if (TR) {
        const float* base = xsrc + (size_t)b * F_DIM * C_DIM;
        const float4* r0 = (const float4*)(base + (size_t)a.x * C_DIM);
        const float4* r1 = (const float4*)(base + (size_t)a.y * C_DIM);
        const float4* r2 = (const float4*)(base + (size_t)a.z * C_DIM);
        const float4* r3 = (const float4*)(base + (size_t)a.w * C_DIM);
        #pragma unroll
        for (int i = 0; i < 16; ++i) {
            const float4 t4 = r0[i], n1 = r1[i], n2 = r2[i], n3 = r3[i];
            tg[4*i+0] = t4.x;
            tg[4*i+1] = t4.y;
            tg[4*i+2] = t4.z;
            tg[4*i+3] = t4.w;
            bt[4*i+0] = fabsf(t4.x-n1.x) + fabsf(t4.x-n2.x) + fabsf(t4.x-n3.x);
            bt[4*i+1] = fabsf(t4.y-n1.y) + fabsf(t4.y-n2.y) + fabsf(t4.y-n3.y);
            bt[4*i+2] = fabsf(t4.z-n1.z) + fabsf(t4.z-n2.z) + fabsf(t4.z-n3.z);
            bt[4*i+3] = fabsf(t4.w-n1.w) + fabsf(t4.w-n2.w) + fabsf(t4.w-n3.w);
        }
    } else {
        const float* base = xsrc + (size_t)b * C_DIM * F_DIM;
        #pragma unroll
        for (int c = 0; c < 64; ++c) {
            const float tv = base[(size_t)c * F_DIM + a.x];
            const float n1 = base[(size_t)c * F_DIM + a.y];
            const float n2 = base[(size_t)c * F_DIM + a.z];
            const float n3 = base[(size_t)c * F_DIM + a.w];
            tg[c] = tv;
            bt[c] = fabsf(tv-n1) + fabsf(tv-n2) + fabsf(tv-n3);
        }
    }

    float* yb = y + (size_t)b * O_DIM * F_DIM + f;
    const float2* W2 = (const float2*)W;   // W[o][c][0..1]
    #pragma unroll 4
    for (int o = 0; o < O_DIM; ++o) {
        float acc = bias[o];               // uniform -> scalar load
        #pragma unroll
        for (int c = 0; c < 64; ++c) {
            const float2 w = W2[o * 64 + c];  // uniform -> scalar load
            acc = fmaf(tg[c], w.x, fmaf(bt[c], w.y, acc));
        }
        yb[(size_t)o * F_DIM] = acc;       // coalesced over f
    }
}

// ---------------- Pass 3a: per-o sum / sumsq over (b,f) ---------------------
__global__ __launch_bounds__(256) void k_stats(const float* __restrict__ y,
                                               float* __restrict__ stats) {
    const int o = blockIdx.x;
    const int b = blockIdx.y;
    const float4* row = (const float4*)(y + ((size_t)b * O_DIM + o) * F_DIM);
    float s = 0.f, s2 = 0.f;
    for (int i = threadIdx.x; i < F_DIM / 4; i += 256) {
        const float4 v = row[i];
        s  += v.x + v.y + v.z + v.w;
        s2 += v.x*v.x + v.y*v.y + v.z*v.z + v.w*v.w;
    }
    #pragma unroll
    for (int off = 32; off > 0; off >>= 1) {
        s  += __shfl_down(s,  off, 64);
        s2 += __shfl_down(s2, off, 64);
    }
    __shared__ float ls[4], ls2[4];
    const int wid = threadIdx.x >> 6, lane = threadIdx.x & 63;
    if (lane == 0) { ls[wid] = s; ls2[wid] = s2; }
    __syncthreads();
    if (threadIdx.x == 0) {
        const float ts  = ls[0] + ls[1] + ls[2] + ls[3];
        const float ts2 = ls2[0] + ls2[1] + ls2[2] + ls2[3];
        atomicAdd(&stats[o],         ts);
        atomicAdd(&stats[O_DIM + o], ts2);
    }
}

// ---------------- Pass 3a2: finalize scale/shift ----------------------------
__global__ void k_finalize(const float* __restrict__ stats,
                           const float* __restrict__ gamma,
                           const float* __restrict__ beta_bn,
                           float* __restrict__ ss) {
    const int o = threadIdx.x;
    if (o < O_DIM) {
        const float n    = (float)B_DIM * (float)F_DIM;
        const float mean = stats[o] / n;
        const float var  = stats[O_DIM + o] / n - mean * mean;
        const float rstd = rsqrtf(var + 1e-5f);
        const float sc   = gamma[o] * rstd;
        ss[o]         = sc;
        ss[O_DIM + o] = beta_bn[o] - mean * sc;
    }
}

// ---------------- Pass 3b: normalize + ReLU in place ------------------------
__global__ __launch_bounds__(256) void k_norm(float* __restrict__ y,
                                              const float* __restrict__ ss) {
    const size_t n4 = (size_t)B_DIM * O_DIM * F_DIM / 4;
    const size_t stride = (size_t)gridDim.x * blockDim.x;
    float4* y4 = (float4*)y;
    for (size_t i = (size_t)blockIdx.x * blockDim.x + threadIdx.x; i < n4; i += stride) {
        const int o = (int)((i >> 12) & (O_DIM - 1));   // i*4/16384 % 128
        const float sc = ss[o];
        const float sh = ss[O_DIM + o];
        float4 v = y4[i];
        v.x = fmaxf(fmaf(v.x, sc, sh), 0.f);
        v.y = fmaxf(fmaf(v.y, sc, sh), 0.f);
        v.z = fmaxf(fmaf(v.z, sc, sh), 0.f);
        v.w = fmaxf(fmaf(v.w, sc, sh), 0.f);
        y4[i] = v;
    }
}

extern "C" void kernel_launch(void* const* d_in, const int* in_sizes, int n_in,
                              void* d_out, int out_size, void* d_ws, size_t ws_size,
                              hipStream_t stream) {
    const float* x       = (const float*)d_in[0];
    const int*   adj     = (const int*)  d_in[1];
    const float* W       = (const float*)d_in[2];
    const float* bias    = (const float*)d_in[3];
    const float* gamma   = (const float*)d_in[4];
    const float* beta_bn = (const float*)d_in[5];
    float* out = (float*)d_out;

    float* stats = (float*)d_ws;                 // 256 floats (sum, sumsq)
    float* ss    = stats + 2 * O_DIM;            // 256 floats (scale, shift)
    float* xt    = (float*)((char*)d_ws + 4096);
    const size_t need = 4096 + (size_t)B_DIM * F_DIM * C_DIM * sizeof(float);

    hipMemsetAsync(stats, 0, 2 * O_DIM * sizeof(float), stream);

    if (ws_size >= need) {
        k_transpose<<<dim3(F_DIM / 64, B_DIM), 256, 0, stream>>>(x, xt);
        k_compute<true><<<dim3(F_DIM / 256, B_DIM), 256, 0, stream>>>(xt, adj, W, bias, out);
    } else {
        k_compute<false><<<dim3(F_DIM / 256, B_DIM), 256, 0, stream>>>(x, adj, W, bias, out);
    }
    k_stats<<<dim3(O_DIM, B_DIM), 256, 0, stream>>>(out, stats);
    k_finalize<<<1, 128, 0, stream>>>(stats, gamma, beta_bn, ss);
    k_norm<<<2048, 256, 0, stream>>>(out, ss);
}

// Round 2
// 326.074 us; speedup vs baseline: 4.9537x; 4.9537x over previous
//
#include <hip/hip_runtime.h>

#define B_DIM 32
#define C_DIM 64
#define F_DIM 16384
#define O_DIM 128

typedef __attribute__((ext_vector_type(8))) short short8;
typedef __attribute__((ext_vector_type(4))) float f32x4;

__device__ __forceinline__ ushort f2bf(float f) {
    union { float f; uint u; } v; v.f = f;
    return (ushort)((v.u + 0x7FFFu + ((v.u >> 16) & 1u)) >> 16);
}
__device__ __forceinline__ float bflo(uint u) {
    union { uint u; float f; } v; v.u = u << 16; return v.f;
}
__device__ __forceinline__ float bfhi(uint u) {
    union { uint u; float f; } v; v.u = u & 0xFFFF0000u; return v.f;
}

// ---------------- Pass 0: W (O,C,2) fp32 -> Wt[o][k] bf16, k-contiguous -----
__global__ void k_prepw(const float* __restrict__ W, ushort* __restrict__ Wtg) {
    const int o = threadIdx.x;
    if (o < O_DIM) {
        for (int c = 0; c < C_DIM; ++c) {
            Wtg[o * 128 + c]      = f2bf(W[o * 128 + c * 2]);
            Wtg[o * 128 + 64 + c] = f2bf(W[o * 128 + c * 2 + 1]);
        }
    }
}

// ---------------- Pass 1: transpose x (B,C,F) fp32 -> xt (B,F,C) bf16 -------
__global__ __launch_bounds__(256) void k_transpose(const float* __restrict__ x,
                                                   ushort* __restrict__ xt) {
    __shared__ float tile[64][65];
    const int b  = blockIdx.y;
    const int f0 = blockIdx.x * 64;
    const int t  = threadIdx.x;
    const int fl = t & 63;
    const int q  = t >> 6;

    const float* xb = x + (size_t)b * C_DIM * F_DIM;
    #pragma unroll
    for (int i = 0; i < 16; ++i) {
        const int c = q + i * 4;
        tile[c][fl] = xb[(size_t)c * F_DIM + f0 + fl];
    }
    __syncthreads();
    ushort* xtb = xt + ((size_t)b * F_DIM + f0) * C_DIM;
    #pragma unroll
    for (int i = 0; i < 16; ++i) {
        const int f = q + i * 4;
        xtb[(size_t)f * C_DIM + fl] = f2bf(tile[fl][f]);
    }
}

// ------------- Pass 2: gather + beta + MFMA GEMM, y -> d_out (B,O,F) --------
__global__ __launch_bounds__(256, 3) void k_compute(const ushort* __restrict__ xt,
                                                    const int*    __restrict__ adj,
                                                    const ushort* __restrict__ Wtg,
                                                    const float*  __restrict__ bias,
                                                    float*        __restrict__ y) {
    __shared__ __align__(16) char Asm[64 * 256];    // A tile: 64 rows x 128 bf16 (swizzled)
    __shared__ __align__(16) char Wsm[128 * 256];   // Wt:   128 rows x 128 bf16 (swizzled)

    const int b  = blockIdx.y;
    const int f0 = blockIdx.x * 64;
    const int t  = threadIdx.x;

    // --- stage Wt (pre-converted bf16, linear) into swizzled LDS ---
    {
        const uint4* src = (const uint4*)Wtg;
        #pragma unroll
        for (int j = 0; j < 8; ++j) {
            const int fb   = t * 128 + j * 16;              // flat byte
            const int o    = fb >> 8;
            const int inner= fb & 255;
            *(uint4*)(Wsm + (o << 8) + (inner ^ ((o & 7) << 4))) = src[fb >> 4];
        }
    }

    // --- gather + beta into swizzled A tile ---
    {
        const int p  = t >> 2;          // point 0..63
        const int ch = t & 3;           // c-chunk of 16
        const int4 a4 = ((const int4*)adj)[(size_t)b * F_DIM + f0 + p];
        const char* xb = (const char*)(xt + (size_t)b * F_DIM * C_DIM);
        const char* r0 = xb + (size_t)a4.x * 128 + ch * 32;
        const char* r1 = xb + (size_t)a4.y * 128 + ch * 32;
        const char* r2 = xb + (size_t)a4.z * 128 + ch * 32;
        const char* r3 = xb + (size_t)a4.w * 128 + ch * 32;
        const int sw = (p & 7) << 4;
        char* Arow = Asm + p * 256;
        #pragma unroll
        for (int h = 0; h < 2; ++h) {
            const uint4 t0 = *(const uint4*)(r0 + h * 16);
            const uint4 n1 = *(const uint4*)(r1 + h * 16);
            const uint4 n2 = *(const uint4*)(r2 + h * 16);
            const uint4 n3 = *(const uint4*)(r3 + h * 16);
            // target: already bf16 — copy bits straight in
            *(uint4*)(Arow + ((ch * 32 + h * 16) ^ sw)) = t0;
            // beta: fp32 compute, round to bf16
            const uint tu[4] = { t0.x, t0.y, t0.z, t0.w };
            const uint au[4] = { n1.x, n1.y, n1.z, n1.w };
            const uint bu[4] = { n2.x, n2.y, n2.z, n2.w };
            const uint cu[4] = { n3.x, n3.y, n3.z, n3.w };
            uint bt[4];
            #pragma unroll
            for (int q = 0; q < 4; ++q) {
                const float tl = bflo(tu[q]), th = bfhi(tu[q]);
                const float lo = fabsf(tl - bflo(au[q])) + fabsf(tl - bflo(bu[q])) + fabsf(tl - bflo(cu[q]));
                const float hi = fabsf(th - bfhi(au[q])) + fabsf(th - bfhi(bu[q])) + fabsf(th - bfhi(cu[q]));
                bt[q] = (uint)f2bf(lo) | ((uint)f2bf(hi) << 16);
            }
            *(uint4*)(Arow + ((128 + ch * 32 + h * 16) ^ sw)) =
                make_uint4(bt[0], bt[1], bt[2], bt[3]);
        }
    }

    __syncthreads();

    // --- MFMA: wave w owns m-rows [w*16, w*16+16), all 128 o ---
    const int w     = t >> 6;
    const int l     = t & 63;
    const int col16 = l & 15;
    const int g     = l >> 4;
    const int swl   = (l & 7) << 4;

    f32x4 acc[8];
    #pragma unroll
    for (int s = 0; s < 8; ++s) {
        const float bv = bias[s * 16 + col16];
        acc[s] = (f32x4){ bv, bv, bv, bv };
    }

    const char* ArowR = Asm + (w * 16 + col16) * 256;
    #pragma unroll
    for (int kk = 0; kk < 4; ++kk) {
        const int koff = kk * 64 + g * 16;
        const short8 af = *(const short8*)(ArowR + (koff ^ swl));
        #pragma unroll
        for (int s = 0; s < 8; ++s) {
            const short8 bf = *(const short8*)(Wsm + (s * 16 + col16) * 256 + (koff ^ swl));
            acc[s] = __builtin_amdgcn_mfma_f32_16x16x32_bf16(af, bf, acc[s], 0, 0, 0);
        }
    }

    // --- epilogue: coalesced float4 stores ---
    const int fbase = f0 + w * 16 + g * 4;
    #pragma unroll
    for (int s = 0; s < 8; ++s) {
        const int o = s * 16 + col16;
        *(f32x4*)(y + ((size_t)b * O_DIM + o) * F_DIM + fbase) = acc[s];
    }
}

// -------- fallback (no-transpose, fp32 vector) — round-1 known-correct ------
__global__ __launch_bounds__(256) void k_compute_slow(const float* __restrict__ xsrc,
                                                      const int*   __restrict__ adj,
                                                      const float* __restrict__ W,
                                                      const float* __restrict__ bias,
                                                      float*       __restrict__ y) {
    const int b = blockIdx.y;
    const int f = blockIdx.x * 256 + threadIdx.x;
    const int4 a = ((const int4*)adj)[(size_t)b * F_DIM + f];
    float tg[64], bt[64];
    const float* base = xsrc + (size_t)b * C_DIM * F_DIM;
    #pragma unroll
    for (int c = 0; c < 64; ++c) {
        const float tv = base[(size_t)c * F_DIM + a.x];
        const float n1 = base[(size_t)c * F_DIM + a.y];
        const float n2 = base[(size_t)c * F_DIM + a.z];
        const float n3 = base[(size_t)c * F_DIM + a.w];
        tg[c] = tv;
        bt[c] = fabsf(tv - n1) + fabsf(tv - n2) + fabsf(tv - n3);
    }
    float* yb = y + (size_t)b * O_DIM * F_DIM + f;
    const float2* W2 = (const float2*)W;
    #pragma unroll 4
    for (int o = 0; o < O_DIM; ++o) {
        float acc = bias[o];
        #pragma unroll
        for (int c = 0; c < 64; ++c) {
            const float2 wv = W2[o * 64 + c];
            acc = fmaf(tg[c], wv.x, fmaf(bt[c], wv.y, acc));
        }
        yb[(size_t)o * F_DIM] = acc;
    }
}

// ---------------- Pass 3a: per-o sum / sumsq over (b,f) ---------------------
__global__ __launch_bounds__(256) void k_stats(const float* __restrict__ y,
                                               float* __restrict__ stats) {
    const int o = blockIdx.x;
    const int b = blockIdx.y;
    const float4* row = (const float4*)(y + ((size_t)b * O_DIM + o) * F_DIM);
    float s = 0.f, s2 = 0.f;
    for (int i = threadIdx.x; i < F_DIM / 4; i += 256) {
        const float4 v = row[i];
        s  += v.x + v.y + v.z + v.w;
        s2 += v.x * v.x + v.y * v.y + v.z * v.z + v.w * v.w;
    }
    #pragma unroll
    for (int off = 32; off > 0; off >>= 1) {
        s  += __shfl_down(s,  off, 64);
        s2 += __shfl_down(s2, off, 64);
    }
    __shared__ float ls[4], ls2[4];
    const int wid = threadIdx.x >> 6, lane = threadIdx.x & 63;
    if (lane == 0) { ls[wid] = s; ls2[wid] = s2; }
    __syncthreads();
    if (threadIdx.x == 0) {
        atomicAdd(&stats[o],         ls[0] + ls[1] + ls[2] + ls[3]);
        atomicAdd(&stats[O_DIM + o], ls2[0] + ls2[1] + ls2[2] + ls2[3]);
    }
}

// ---------------- Pass 3a2: finalize scale/shift ----------------------------
__global__ void k_finalize(const float* __restrict__ stats,
                           const float* __restrict__ gamma,
                           const float* __restrict__ beta_bn,
                           float* __restrict__ ss) {
    const int o = threadIdx.x;
    if (o < O_DIM) {
        const float n    = (float)B_DIM * (float)F_DIM;
        const float mean = stats[o] / n;
        const float var  = stats[O_DIM + o] / n - mean * mean;
        const float sc   = gamma[o] * rsqrtf(var + 1e-5f);
        ss[o]         = sc;
        ss[O_DIM + o] = beta_bn[o] - mean * sc;
    }
}

// ---------------- Pass 3b: normalize + ReLU in place ------------------------
__global__ __launch_bounds__(256) void k_norm(float* __restrict__ y,
                                              const float* __restrict__ ss) {
    const size_t n4 = (size_t)B_DIM * O_DIM * F_DIM / 4;
    const size_t stride = (size_t)gridDim.x * blockDim.x;
    float4* y4 = (float4*)y;
    for (size_t i = (size_t)blockIdx.x * blockDim.x + threadIdx.x; i < n4; i += stride) {
        const int o = (int)((i >> 12) & (O_DIM - 1));
        const float sc = ss[o];
        const float sh = ss[O_DIM + o];
        float4 v = y4[i];
        v.x = fmaxf(fmaf(v.x, sc, sh), 0.f);
        v.y = fmaxf(fmaf(v.y, sc, sh), 0.f);
        v.z = fmaxf(fmaf(v.z, sc, sh), 0.f);
        v.w = fmaxf(fmaf(v.w, sc, sh), 0.f);
        y4[i] = v;
    }
}

extern "C" void kernel_launch(void* const* d_in, const int* in_sizes, int n_in,
                              void* d_out, int out_size, void* d_ws, size_t ws_size,
                              hipStream_t stream) {
    const float* x       = (const float*)d_in[0];
    const int*   adj     = (const int*)  d_in[1];
    const float* W       = (const float*)d_in[2];
    const float* bias    = (const float*)d_in[3];
    const float* gamma   = (const float*)d_in[4];
    const float* beta_bn = (const float*)d_in[5];
    float* out = (float*)d_out;

    float*  stats = (float*)d_ws;                        // 256 f
    float*  ss    = (float*)((char*)d_ws + 1024);        // 256 f
    ushort* Wtg   = (ushort*)((char*)d_ws + 4096);       // 32 KB
    ushort* xt    = (ushort*)((char*)d_ws + 65536);      // 64 MB bf16
    const size_t need = 65536 + (size_t)B_DIM * F_DIM * C_DIM * sizeof(ushort);

    hipMemsetAsync(stats, 0, 2 * O_DIM * sizeof(float), stream);

    if (ws_size >= need) {
        k_prepw<<<1, 128, 0, stream>>>(W, Wtg);
        k_transpose<<<dim3(F_DIM / 64, B_DIM), 256, 0, stream>>>(x, xt);
        k_compute<<<dim3(F_DIM / 64, B_DIM), 256, 0, stream>>>(xt, adj, Wtg, bias, out);
    } else {
        k_compute_slow<<<dim3(F_DIM / 256, B_DIM), 256, 0, stream>>>(x, adj, W, bias, out);
    }
    k_stats<<<dim3(O_DIM, B_DIM), 256, 0, stream>>>(out, stats);
    k_finalize<<<1, 128, 0, stream>>>(stats, gamma, beta_bn, ss);
    k_norm<<<2048, 256, 0, stream>>>(out, ss);
}

// Round 3
// 221.867 us; speedup vs baseline: 7.2803x; 1.4697x over previous
//
#include <hip/hip_runtime.h>

#define B_DIM 32
#define C_DIM 64
#define F_DIM 16384
#define O_DIM 128
#define NBLK ((F_DIM / 64) * B_DIM)   // 8192 compute blocks

typedef __attribute__((ext_vector_type(8))) short short8;
typedef __attribute__((ext_vector_type(4))) float f32x4;

__device__ __forceinline__ ushort f2bf(float f) {
    union { float f; uint u; } v; v.f = f;
    return (ushort)((v.u + 0x7FFFu + ((v.u >> 16) & 1u)) >> 16);
}
__device__ __forceinline__ float bflo(uint u) {
    union { uint u; float f; } v; v.u = u << 16; return v.f;
}
__device__ __forceinline__ float bfhi(uint u) {
    union { uint u; float f; } v; v.u = u & 0xFFFF0000u; return v.f;
}

// ---------------- Pass 0: W (O,C,2) fp32 -> Wt[o][k] bf16, k-contiguous -----
__global__ void k_prepw(const float* __restrict__ W, ushort* __restrict__ Wtg) {
    const int o = threadIdx.x;
    if (o < O_DIM) {
        for (int c = 0; c < C_DIM; ++c) {
            Wtg[o * 128 + c]      = f2bf(W[o * 128 + c * 2]);
            Wtg[o * 128 + 64 + c] = f2bf(W[o * 128 + c * 2 + 1]);
        }
    }
}

// ---------------- Pass 1: transpose x (B,C,F) fp32 -> xt (B,F,C) bf16 -------
__global__ __launch_bounds__(256) void k_transpose(const float* __restrict__ x,
                                                   ushort* __restrict__ xt) {
    __shared__ float tile[64][65];
    const int b  = blockIdx.y;
    const int f0 = blockIdx.x * 64;
    const int t  = threadIdx.x;
    const int fl = t & 63;
    const int q  = t >> 6;

    const float* xb = x + (size_t)b * C_DIM * F_DIM;
    #pragma unroll
    for (int i = 0; i < 16; ++i) {
        const int c = q + i * 4;
        tile[c][fl] = xb[(size_t)c * F_DIM + f0 + fl];
    }
    __syncthreads();
    ushort* xtb = xt + ((size_t)b * F_DIM + f0) * C_DIM;
    #pragma unroll
    for (int i = 0; i < 16; ++i) {
        const int f = q + i * 4;
        xtb[(size_t)f * C_DIM + fl] = f2bf(tile[fl][f]);
    }
}

// ------------- Pass 2/4: gather + beta + MFMA GEMM ---------------------------
// MODE 0: accumulate per-block (sum,sumsq) per o -> part, no y store.
// MODE 1: apply scale/shift (ss) + ReLU, store final y.
template <int MODE>
__global__ __launch_bounds__(256, 3) void k_compute_t(const ushort* __restrict__ xt,
                                                      const int*    __restrict__ adj,
                                                      const ushort* __restrict__ Wtg,
                                                      const float*  __restrict__ bias,
                                                      const float*  __restrict__ ss,
                                                      float*        __restrict__ y,
                                                      float*        __restrict__ part) {
    __shared__ __align__(16) char Asm[64 * 256];    // A tile: 64 rows x 128 bf16 (swizzled)
    __shared__ __align__(16) char Wsm[128 * 256];   // Wt:   128 rows x 128 bf16 (swizzled)

    const int b  = blockIdx.y;
    const int f0 = blockIdx.x * 64;
    const int t  = threadIdx.x;

    // --- stage Wt (pre-converted bf16, linear) into swizzled LDS ---
    {
        const uint4* src = (const uint4*)Wtg;
        #pragma unroll
        for (int j = 0; j < 8; ++j) {
            const int fb    = t * 128 + j * 16;
            const int o     = fb >> 8;
            const int inner = fb & 255;
            *(uint4*)(Wsm + (o << 8) + (inner ^ ((o & 7) << 4))) = src[fb >> 4];
        }
    }

    // --- gather + beta into swizzled A tile ---
    {
        const int p  = t >> 2;          // point 0..63
        const int ch = t & 3;           // c-chunk of 16
        const int4 a4 = ((const int4*)adj)[(size_t)b * F_DIM + f0 + p];
        const char* xb = (const char*)(xt + (size_t)b * F_DIM * C_DIM);
        const char* r0 = xb + (size_t)a4.x * 128 + ch * 32;
        const char* r1 = xb + (size_t)a4.y * 128 + ch * 32;
        const char* r2 = xb + (size_t)a4.z * 128 + ch * 32;
        const char* r3 = xb + (size_t)a4.w * 128 + ch * 32;
        const int sw = (p & 7) << 4;
        char* Arow = Asm + p * 256;
        #pragma unroll
        for (int h = 0; h < 2; ++h) {
            const uint4 t0 = *(const uint4*)(r0 + h * 16);
            const uint4 n1 = *(const uint4*)(r1 + h * 16);
            const uint4 n2 = *(const uint4*)(r2 + h * 16);
            const uint4 n3 = *(const uint4*)(r3 + h * 16);
            *(uint4*)(Arow + ((ch * 32 + h * 16) ^ sw)) = t0;   // target bits
            const uint tu[4] = { t0.x, t0.y, t0.z, t0.w };
            const uint au[4] = { n1.x, n1.y, n1.z, n1.w };
            const uint bu[4] = { n2.x, n2.y, n2.z, n2.w };
            const uint cu[4] = { n3.x, n3.y, n3.z, n3.w };
            uint bt[4];
            #pragma unroll
            for (int q = 0; q < 4; ++q) {
                const float tl = bflo(tu[q]), th = bfhi(tu[q]);
                const float lo = fabsf(tl - bflo(au[q])) + fabsf(tl - bflo(bu[q])) + fabsf(tl - bflo(cu[q]));
                const float hi = fabsf(th - bfhi(au[q])) + fabsf(th - bfhi(bu[q])) + fabsf(th - bfhi(cu[q]));
                bt[q] = (uint)f2bf(lo) | ((uint)f2bf(hi) << 16);
            }
            *(uint4*)(Arow + ((128 + ch * 32 + h * 16) ^ sw)) =
                make_uint4(bt[0], bt[1], bt[2], bt[3]);
        }
    }

    __syncthreads();

    // --- MFMA: wave w owns m-rows [w*16, w*16+16), all 128 o ---
    const int w     = t >> 6;
    const int l     = t & 63;
    const int col16 = l & 15;
    const int g     = l >> 4;
    const int swl   = (l & 7) << 4;

    f32x4 acc[8];
    #pragma unroll
    for (int s = 0; s < 8; ++s) {
        const float bv = bias[s * 16 + col16];
        acc[s] = (f32x4){ bv, bv, bv, bv };
    }

    const char* ArowR = Asm + (w * 16 + col16) * 256;
    #pragma unroll
    for (int kk = 0; kk < 4; ++kk) {
        const int koff = kk * 64 + g * 16;
        const short8 af = *(const short8*)(ArowR + (koff ^ swl));
        #pragma unroll
        for (int s = 0; s < 8; ++s) {
            const short8 bf = *(const short8*)(Wsm + (s * 16 + col16) * 256 + (koff ^ swl));
            acc[s] = __builtin_amdgcn_mfma_f32_16x16x32_bf16(af, bf, acc[s], 0, 0, 0);
        }
    }

    if (MODE == 0) {
        // --- reduce acc -> per-block (sum,sumsq) per o, write partials ---
        __shared__ float sm_s[4][128];
        __shared__ float sm_q[4][128];
        #pragma unroll
        for (int s = 0; s < 8; ++s) {
            float ps = acc[s].x + acc[s].y + acc[s].z + acc[s].w;
            float pq = acc[s].x * acc[s].x + acc[s].y * acc[s].y
                     + acc[s].z * acc[s].z + acc[s].w * acc[s].w;
            ps += __shfl_xor(ps, 16, 64);  pq += __shfl_xor(pq, 16, 64);
            ps += __shfl_xor(ps, 32, 64);  pq += __shfl_xor(pq, 32, 64);
            if (g == 0) {
                sm_s[w][s * 16 + col16] = ps;
                sm_q[w][s * 16 + col16] = pq;
            }
        }
        __syncthreads();
        if (t < 128) {
            const float a = sm_s[0][t] + sm_s[1][t] + sm_s[2][t] + sm_s[3][t];
            const float c = sm_q[0][t] + sm_q[1][t] + sm_q[2][t] + sm_q[3][t];
            const int blk = blockIdx.y * gridDim.x + blockIdx.x;
            part[(size_t)t * NBLK + blk]         = a;
            part[(size_t)(128 + t) * NBLK + blk] = c;
        }
    } else {
        // --- normalize + ReLU + coalesced float4 stores ---
        const int fbase = f0 + w * 16 + g * 4;
        #pragma unroll
        for (int s = 0; s < 8; ++s) {
            const int o = s * 16 + col16;
            const float sc = ss[o];
            const float sh = ss[O_DIM + o];
            f32x4 v = acc[s];
            v.x = fmaxf(fmaf(v.x, sc, sh), 0.f);
            v.y = fmaxf(fmaf(v.y, sc, sh), 0.f);
            v.z = fmaxf(fmaf(v.z, sc, sh), 0.f);
            v.w = fmaxf(fmaf(v.w, sc, sh), 0.f);
            *(f32x4*)(y + ((size_t)b * O_DIM + o) * F_DIM + fbase) = v;
        }
    }
}

// ------------- Pass 3: reduce partials + finalize scale/shift ---------------
__global__ __launch_bounds__(256) void k_reduce_finalize(const float* __restrict__ part,
                                                         const float* __restrict__ gamma,
                                                         const float* __restrict__ beta_bn,
                                                         float* __restrict__ ss) {
    const int o = blockIdx.x;   // 0..127
    const int t = threadIdx.x;
    const float4* p1 = (const float4*)(part + (size_t)o * NBLK);
    const float4* p2 = (const float4*)(part + (size_t)(128 + o) * NBLK);
    float s = 0.f, q = 0.f;
    for (int i = t; i < NBLK / 4; i += 256) {
        const float4 v = p1[i];
        s += v.x + v.y + v.z + v.w;
        const float4 u = p2[i];
        q += u.x + u.y + u.z + u.w;
    }
    #pragma unroll
    for (int off = 32; off > 0; off >>= 1) {
        s += __shfl_down(s, off, 64);
        q += __shfl_down(q, off, 64);
    }
    __shared__ float ls[8];
    const int wid = t >> 6, lane = t & 63;
    if (lane == 0) { ls[wid] = s; ls[4 + wid] = q; }
    __syncthreads();
    if (t == 0) {
        const float ts = ls[0] + ls[1] + ls[2] + ls[3];
        const float tq = ls[4] + ls[5] + ls[6] + ls[7];
        const float n    = (float)B_DIM * (float)F_DIM;
        const float mean = ts / n;
        const float var  = tq / n - mean * mean;
        const float sc   = gamma[o] * rsqrtf(var + 1e-5f);
        ss[o]         = sc;
        ss[O_DIM + o] = beta_bn[o] - mean * sc;
    }
}

// ================== fallback path (small ws) — round-1 known-correct ========
__global__ __launch_bounds__(256) void k_compute_slow(const float* __restrict__ xsrc,
                                                      const int*   __restrict__ adj,
                                                      const float* __restrict__ W,
                                                      const float* __restrict__ bias,
                                                      float*       __restrict__ y) {
    const int b = blockIdx.y;
    const int f = blockIdx.x * 256 + threadIdx.x;
    const int4 a = ((const int4*)adj)[(size_t)b * F_DIM + f];
    float tg[64], bt[64];
    const float* base = xsrc + (size_t)b * C_DIM * F_DIM;
    #pragma unroll
    for (int c = 0; c < 64; ++c) {
        const float tv = base[(size_t)c * F_DIM + a.x];
        const float n1 = base[(size_t)c * F_DIM + a.y];
        const float n2 = base[(size_t)c * F_DIM + a.z];
        const float n3 = base[(size_t)c * F_DIM + a.w];
        tg[c] = tv;
        bt[c] = fabsf(tv - n1) + fabsf(tv - n2) + fabsf(tv - n3);
    }
    float* yb = y + (size_t)b * O_DIM * F_DIM + f;
    const float2* W2 = (const float2*)W;
    #pragma unroll 4
    for (int o = 0; o < O_DIM; ++o) {
        float acc = bias[o];
        #pragma unroll
        for (int c = 0; c < 64; ++c) {
            const float2 wv = W2[o * 64 + c];
            acc = fmaf(tg[c], wv.x, fmaf(bt[c], wv.y, acc));
        }
        yb[(size_t)o * F_DIM] = acc;
    }
}

__global__ __launch_bounds__(256) void k_stats(const float* __restrict__ y,
                                               float* __restrict__ stats) {
    const int o = blockIdx.x;
    const int b = blockIdx.y;
    const float4* row = (const float4*)(y + ((size_t)b * O_DIM + o) * F_DIM);
    float s = 0.f, s2 = 0.f;
    for (int i = threadIdx.x; i < F_DIM / 4; i += 256) {
        const float4 v = row[i];
        s  += v.x + v.y + v.z + v.w;
        s2 += v.x * v.x + v.y * v.y + v.z * v.z + v.w * v.w;
    }
    #pragma unroll
    for (int off = 32; off > 0; off >>= 1) {
        s  += __shfl_down(s,  off, 64);
        s2 += __shfl_down(s2, off, 64);
    }
    __shared__ float ls[4], ls2[4];
    const int wid = threadIdx.x >> 6, lane = threadIdx.x & 63;
    if (lane == 0) { ls[wid] = s; ls2[wid] = s2; }
    __syncthreads();
    if (threadIdx.x == 0) {
        atomicAdd(&stats[o],         ls[0] + ls[1] + ls[2] + ls[3]);
        atomicAdd(&stats[O_DIM + o], ls2[0] + ls2[1] + ls2[2] + ls2[3]);
    }
}

__global__ void k_finalize(const float* __restrict__ stats,
                           const float* __restrict__ gamma,
                           const float* __restrict__ beta_bn,
                           float* __restrict__ ss) {
    const int o = threadIdx.x;
    if (o < O_DIM) {
        const float n    = (float)B_DIM * (float)F_DIM;
        const float mean = stats[o] / n;
        const float var  = stats[O_DIM + o] / n - mean * mean;
        const float sc   = gamma[o] * rsqrtf(var + 1e-5f);
        ss[o]         = sc;
        ss[O_DIM + o] = beta_bn[o] - mean * sc;
    }
}

__global__ __launch_bounds__(256) void k_norm(float* __restrict__ y,
                                              const float* __restrict__ ss) {
    const size_t n4 = (size_t)B_DIM * O_DIM * F_DIM / 4;
    const size_t stride = (size_t)gridDim.x * blockDim.x;
    float4* y4 = (float4*)y;
    for (size_t i = (size_t)blockIdx.x * blockDim.x + threadIdx.x; i < n4; i += stride) {
        const int o = (int)((i >> 12) & (O_DIM - 1));
        const float sc = ss[o];
        const float sh = ss[O_DIM + o];
        float4 v = y4[i];
        v.x = fmaxf(fmaf(v.x, sc, sh), 0.f);
        v.y = fmaxf(fmaf(v.y, sc, sh), 0.f);
        v.z = fmaxf(fmaf(v.z, sc, sh), 0.f);
        v.w = fmaxf(fmaf(v.w, sc, sh), 0.f);
        y4[i] = v;
    }
}

extern "C" void kernel_launch(void* const* d_in, const int* in_sizes, int n_in,
                              void* d_out, int out_size, void* d_ws, size_t ws_size,
                              hipStream_t stream) {
    const float* x       = (const float*)d_in[0];
    const int*   adj     = (const int*)  d_in[1];
    const float* W       = (const float*)d_in[2];
    const float* bias    = (const float*)d_in[3];
    const float* gamma   = (const float*)d_in[4];
    const float* beta_bn = (const float*)d_in[5];
    float* out = (float*)d_out;

    float*  stats = (float*)d_ws;                        // 256 f (fallback)
    float*  ss    = (float*)((char*)d_ws + 1024);        // 256 f
    ushort* Wtg   = (ushort*)((char*)d_ws + 4096);       // 32 KB
    ushort* xt    = (ushort*)((char*)d_ws + 65536);      // 64 MB bf16
    float*  part  = (float*)((char*)d_ws + 65536 + (size_t)B_DIM * F_DIM * C_DIM * 2);
    const size_t need = 65536 + (size_t)B_DIM * F_DIM * C_DIM * 2
                      + (size_t)2 * O_DIM * NBLK * sizeof(float);   // ~72 MB

    if (ws_size >= need) {
        k_prepw<<<1, 128, 0, stream>>>(W, Wtg);
        k_transpose<<<dim3(F_DIM / 64, B_DIM), 256, 0, stream>>>(x, xt);
        k_compute_t<0><<<dim3(F_DIM / 64, B_DIM), 256, 0, stream>>>(xt, adj, Wtg, bias, nullptr, nullptr, part);
        k_reduce_finalize<<<O_DIM, 256, 0, stream>>>(part, gamma, beta_bn, ss);
        k_compute_t<1><<<dim3(F_DIM / 64, B_DIM), 256, 0, stream>>>(xt, adj, Wtg, bias, ss, out, nullptr);
    } else {
        hipMemsetAsync(stats, 0, 2 * O_DIM * sizeof(float), stream);
        k_compute_slow<<<dim3(F_DIM / 256, B_DIM), 256, 0, stream>>>(x, adj, W, bias, out);
        k_stats<<<dim3(O_DIM, B_DIM), 256, 0, stream>>>(out, stats);
        k_finalize<<<1, 128, 0, stream>>>(stats, gamma, beta_bn, ss);
        k_norm<<<2048, 256, 0, stream>>>(out, ss);
    }
}

// Round 4
// 205.201 us; speedup vs baseline: 7.8716x; 1.0812x over previous
//
#include <hip/hip_runtime.h>

#define B_DIM 32
#define C_DIM 64
#define F_DIM 16384
#define O_DIM 128
#define NBLK ((F_DIM / 64) * B_DIM)   // 8192 compute blocks

typedef __attribute__((ext_vector_type(8))) short short8;
typedef __attribute__((ext_vector_type(4))) float f32x4;

__device__ __forceinline__ ushort f2bf(float f) {
    union { float f; uint u; } v; v.f = f;
    return (ushort)((v.u + 0x7FFFu + ((v.u >> 16) & 1u)) >> 16);
}
__device__ __forceinline__ float bflo(uint u) {
    union { uint u; float f; } v; v.u = u << 16; return v.f;
}
__device__ __forceinline__ float bfhi(uint u) {
    union { uint u; float f; } v; v.u = u & 0xFFFF0000u; return v.f;
}

// ------- Pass 1: transpose x (B,C,F) fp32 -> xt (B,F,C) bf16  (+W prep) -----
__global__ __launch_bounds__(256) void k_transpose(const float* __restrict__ x,
                                                   ushort* __restrict__ xt,
                                                   const float* __restrict__ W,
                                                   ushort* __restrict__ Wtg) {
    __shared__ float tile[64][65];
    const int b  = blockIdx.y;
    const int f0 = blockIdx.x * 64;
    const int t  = threadIdx.x;
    const int fl = t & 63;
    const int q  = t >> 6;

    const float* xb = x + (size_t)b * C_DIM * F_DIM;
    #pragma unroll
    for (int i = 0; i < 16; ++i) {
        const int c = q + i * 4;
        tile[c][fl] = __builtin_nontemporal_load(&xb[(size_t)c * F_DIM + f0 + fl]);
    }

    // fold W prep into one block (independent of tile[]; before sync is fine)
    if (blockIdx.x == 0 && blockIdx.y == 0 && t < 128) {
        const int o = t;
        #pragma unroll 8
        for (int c = 0; c < C_DIM; ++c) {
            Wtg[o * 128 + c]      = f2bf(W[o * 128 + c * 2]);
            Wtg[o * 128 + 64 + c] = f2bf(W[o * 128 + c * 2 + 1]);
        }
    }

    __syncthreads();

    // write phase: thread -> (f = t>>2, ch = t&3), 16 bf16 = 32 B per thread
    const int f  = t >> 2;
    const int ch = t & 3;
    union { ushort s[16]; uint4 v[2]; } u;
    #pragma unroll
    for (int j = 0; j < 16; ++j)
        u.s[j] = f2bf(tile[ch * 16 + j][f]);
    ushort* dst = xt + ((size_t)b * F_DIM + f0 + f) * C_DIM + ch * 16;
    *(uint4*)(dst)     = u.v[0];
    *(uint4*)(dst + 8) = u.v[1];
}

// ------------- Pass 2/4: gather + beta + MFMA GEMM ---------------------------
// MODE 0: accumulate per-block (sum,sumsq) per o -> part, no y store.
// MODE 1: apply scale/shift (ss) + ReLU, store final y (nontemporal).
template <int MODE>
__global__ __launch_bounds__(256, 3) void k_compute_t(const ushort* __restrict__ xt,
                                                      const int*    __restrict__ adj,
                                                      const ushort* __restrict__ Wtg,
                                                      const float*  __restrict__ bias,
                                                      const float*  __restrict__ ss,
                                                      float*        __restrict__ y,
                                                      float*        __restrict__ part) {
    __shared__ __align__(16) char Asm[64 * 256];    // A tile: 64 rows x 128 bf16 (swizzled)
    __shared__ __align__(16) char Wsm[128 * 256];   // Wt:   128 rows x 128 bf16 (swizzled)

    const int b  = blockIdx.y;
    const int f0 = blockIdx.x * 64;
    const int t  = threadIdx.x;

    // --- issue all 8 scattered gather loads FIRST (latency overlap) ---
    const int p  = t >> 2;          // point 0..63
    const int ch = t & 3;           // c-chunk of 16
    const int4 a4 = ((const int4*)adj)[(size_t)b * F_DIM + f0 + p];
    const char* xb = (const char*)(xt + (size_t)b * F_DIM * C_DIM);
    const char* r0 = xb + (size_t)a4.x * 128 + ch * 32;
    const char* r1 = xb + (size_t)a4.y * 128 + ch * 32;
    const char* r2 = xb + (size_t)a4.z * 128 + ch * 32;
    const char* r3 = xb + (size_t)a4.w * 128 + ch * 32;
    uint4 g[8];
    g[0] = *(const uint4*)(r0);  g[1] = *(const uint4*)(r0 + 16);
    g[2] = *(const uint4*)(r1);  g[3] = *(const uint4*)(r1 + 16);
    g[4] = *(const uint4*)(r2);  g[5] = *(const uint4*)(r2 + 16);
    g[6] = *(const uint4*)(r3);  g[7] = *(const uint4*)(r3 + 16);

    // --- stage Wt into swizzled LDS (independent work under gather latency) ---
    {
        const uint4* src = (const uint4*)Wtg;
        #pragma unroll
        for (int j = 0; j < 8; ++j) {
            const int fb    = t * 128 + j * 16;
            const int o     = fb >> 8;
            const int inner = fb & 255;
            *(uint4*)(Wsm + (o << 8) + (inner ^ ((o & 7) << 4))) = src[fb >> 4];
        }
    }

    // --- beta + A-tile store (swizzled) ---
    {
        const int sw = (p & 7) << 4;
        char* Arow = Asm + p * 256;
        #pragma unroll
        for (int h = 0; h < 2; ++h) {
            const uint4 t0 = g[h], n1 = g[2 + h], n2 = g[4 + h], n3 = g[6 + h];
            *(uint4*)(Arow + ((ch * 32 + h * 16) ^ sw)) = t0;   // target bits
            const uint tu[4] = { t0.x, t0.y, t0.z, t0.w };
            const uint au[4] = { n1.x, n1.y, n1.z, n1.w };
            const uint bu[4] = { n2.x, n2.y, n2.z, n2.w };
            const uint cu[4] = { n3.x, n3.y, n3.z, n3.w };
            uint bt[4];
            #pragma unroll
            for (int qq = 0; qq < 4; ++qq) {
                const float tl = bflo(tu[qq]), th = bfhi(tu[qq]);
                const float lo = fabsf(tl - bflo(au[qq])) + fabsf(tl - bflo(bu[qq])) + fabsf(tl - bflo(cu[qq]));
                const float hi = fabsf(th - bfhi(au[qq])) + fabsf(th - bfhi(bu[qq])) + fabsf(th - bfhi(cu[qq]));
                bt[qq] = (uint)f2bf(lo) | ((uint)f2bf(hi) << 16);
            }
            *(uint4*)(Arow + ((128 + ch * 32 + h * 16) ^ sw)) =
                make_uint4(bt[0], bt[1], bt[2], bt[3]);
        }
    }

    __syncthreads();

    // --- MFMA: wave w owns m-rows [w*16, w*16+16), all 128 o ---
    const int w     = t >> 6;
    const int l     = t & 63;
    const int col16 = l & 15;
    const int gg    = l >> 4;
    const int swl   = (l & 7) << 4;

    f32x4 acc[8];
    #pragma unroll
    for (int s = 0; s < 8; ++s) {
        const float bv = bias[s * 16 + col16];
        acc[s] = (f32x4){ bv, bv, bv, bv };
    }

    const char* ArowR = Asm + (w * 16 + col16) * 256;
    #pragma unroll
    for (int kk = 0; kk < 4; ++kk) {
        const int koff = kk * 64 + gg * 16;
        const short8 af = *(const short8*)(ArowR + (koff ^ swl));
        #pragma unroll
        for (int s = 0; s < 8; ++s) {
            const short8 bf = *(const short8*)(Wsm + (s * 16 + col16) * 256 + (koff ^ swl));
            acc[s] = __builtin_amdgcn_mfma_f32_16x16x32_bf16(af, bf, acc[s], 0, 0, 0);
        }
    }

    if (MODE == 0) {
        // --- reduce acc -> per-block (sum,sumsq) per o, write partials ---
        __shared__ float sm_s[4][128];
        __shared__ float sm_q[4][128];
        #pragma unroll
        for (int s = 0; s < 8; ++s) {
            float ps = acc[s].x + acc[s].y + acc[s].z + acc[s].w;
            float pq = acc[s].x * acc[s].x + acc[s].y * acc[s].y
                     + acc[s].z * acc[s].z + acc[s].w * acc[s].w;
            ps += __shfl_xor(ps, 16, 64);  pq += __shfl_xor(pq, 16, 64);
            ps += __shfl_xor(ps, 32, 64);  pq += __shfl_xor(pq, 32, 64);
            if (gg == 0) {
                sm_s[w][s * 16 + col16] = ps;
                sm_q[w][s * 16 + col16] = pq;
            }
        }
        __syncthreads();
        if (t < 128) {
            const float a = sm_s[0][t] + sm_s[1][t] + sm_s[2][t] + sm_s[3][t];
            const float c = sm_q[0][t] + sm_q[1][t] + sm_q[2][t] + sm_q[3][t];
            const int blk = blockIdx.y * gridDim.x + blockIdx.x;
            part[(size_t)t * NBLK + blk]         = a;
            part[(size_t)(128 + t) * NBLK + blk] = c;
        }
    } else {
        // --- normalize + ReLU + coalesced nontemporal float4 stores ---
        const int fbase = f0 + w * 16 + gg * 4;
        #pragma unroll
        for (int s = 0; s < 8; ++s) {
            const int o = s * 16 + col16;
            const float sc = ss[o];
            const float sh = ss[O_DIM + o];
            f32x4 v = acc[s];
            v.x = fmaxf(fmaf(v.x, sc, sh), 0.f);
            v.y = fmaxf(fmaf(v.y, sc, sh), 0.f);
            v.z = fmaxf(fmaf(v.z, sc, sh), 0.f);
            v.w = fmaxf(fmaf(v.w, sc, sh), 0.f);
            __builtin_nontemporal_store(v, (f32x4*)(y + ((size_t)b * O_DIM + o) * F_DIM + fbase));
        }
    }
}

// ------------- Pass 3: reduce partials + finalize scale/shift ---------------
__global__ __launch_bounds__(256) void k_reduce_finalize(const float* __restrict__ part,
                                                         const float* __restrict__ gamma,
                                                         const float* __restrict__ beta_bn,
                                                         float* __restrict__ ss) {
    const int o = blockIdx.x;   // 0..127
    const int t = threadIdx.x;
    const float4* p1 = (const float4*)(part + (size_t)o * NBLK);
    const float4* p2 = (const float4*)(part + (size_t)(128 + o) * NBLK);
    float s = 0.f, q = 0.f;
    for (int i = t; i < NBLK / 4; i += 256) {
        const float4 v = p1[i];
        s += v.x + v.y + v.z + v.w;
        const float4 u = p2[i];
        q += u.x + u.y + u.z + u.w;
    }
    #pragma unroll
    for (int off = 32; off > 0; off >>= 1) {
        s += __shfl_down(s, off, 64);
        q += __shfl_down(q, off, 64);
    }
    __shared__ float ls[8];
    const int wid = t >> 6, lane = t & 63;
    if (lane == 0) { ls[wid] = s; ls[4 + wid] = q; }
    __syncthreads();
    if (t == 0) {
        const float ts = ls[0] + ls[1] + ls[2] + ls[3];
        const float tq = ls[4] + ls[5] + ls[6] + ls[7];
        const float n    = (float)B_DIM * (float)F_DIM;
        const float mean = ts / n;
        const float var  = tq / n - mean * mean;
        const float sc   = gamma[o] * rsqrtf(var + 1e-5f);
        ss[o]         = sc;
        ss[O_DIM + o] = beta_bn[o] - mean * sc;
    }
}

// ================== fallback path (small ws) — round-1 known-correct ========
__global__ __launch_bounds__(256) void k_compute_slow(const float* __restrict__ xsrc,
                                                      const int*   __restrict__ adj,
                                                      const float* __restrict__ W,
                                                      const float* __restrict__ bias,
                                                      float*       __restrict__ y) {
    const int b = blockIdx.y;
    const int f = blockIdx.x * 256 + threadIdx.x;
    const int4 a = ((const int4*)adj)[(size_t)b * F_DIM + f];
    float tg[64], bt[64];
    const float* base = xsrc + (size_t)b * C_DIM * F_DIM;
    #pragma unroll
    for (int c = 0; c < 64; ++c) {
        const float tv = base[(size_t)c * F_DIM + a.x];
        const float n1 = base[(size_t)c * F_DIM + a.y];
        const float n2 = base[(size_t)c * F_DIM + a.z];
        const float n3 = base[(size_t)c * F_DIM + a.w];
        tg[c] = tv;
        bt[c] = fabsf(tv - n1) + fabsf(tv - n2) + fabsf(tv - n3);
    }
    float* yb = y + (size_t)b * O_DIM * F_DIM + f;
    const float2* W2 = (const float2*)W;
    #pragma unroll 4
    for (int o = 0; o < O_DIM; ++o) {
        float acc = bias[o];
        #pragma unroll
        for (int c = 0; c < 64; ++c) {
            const float2 wv = W2[o * 64 + c];
            acc = fmaf(tg[c], wv.x, fmaf(bt[c], wv.y, acc));
        }
        yb[(size_t)o * F_DIM] = acc;
    }
}

__global__ __launch_bounds__(256) void k_stats(const float* __restrict__ y,
                                               float* __restrict__ stats) {
    const int o = blockIdx.x;
    const int b = blockIdx.y;
    const float4* row = (const float4*)(y + ((size_t)b * O_DIM + o) * F_DIM);
    float s = 0.f, s2 = 0.f;
    for (int i = threadIdx.x; i < F_DIM / 4; i += 256) {
        const float4 v = row[i];
        s  += v.x + v.y + v.z + v.w;
        s2 += v.x * v.x + v.y * v.y + v.z * v.z + v.w * v.w;
    }
    #pragma unroll
    for (int off = 32; off > 0; off >>= 1) {
        s  += __shfl_down(s,  off, 64);
        s2 += __shfl_down(s2, off, 64);
    }
    __shared__ float ls[4], ls2[4];
    const int wid = threadIdx.x >> 6, lane = threadIdx.x & 63;
    if (lane == 0) { ls[wid] = s; ls2[wid] = s2; }
    __syncthreads();
    if (threadIdx.x == 0) {
        atomicAdd(&stats[o],         ls[0] + ls[1] + ls[2] + ls[3]);
        atomicAdd(&stats[O_DIM + o], ls2[0] + ls2[1] + ls2[2] + ls2[3]);
    }
}

__global__ void k_finalize(const float* __restrict__ stats,
                           const float* __restrict__ gamma,
                           const float* __restrict__ beta_bn,
                           float* __restrict__ ss) {
    const int o = threadIdx.x;
    if (o < O_DIM) {
        const float n    = (float)B_DIM * (float)F_DIM;
        const float mean = stats[o] / n;
        const float var  = stats[O_DIM + o] / n - mean * mean;
        const float sc   = gamma[o] * rsqrtf(var + 1e-5f);
        ss[o]         = sc;
        ss[O_DIM + o] = beta_bn[o] - mean * sc;
    }
}

__global__ __launch_bounds__(256) void k_norm(float* __restrict__ y,
                                              const float* __restrict__ ss) {
    const size_t n4 = (size_t)B_DIM * O_DIM * F_DIM / 4;
    const size_t stride = (size_t)gridDim.x * blockDim.x;
    float4* y4 = (float4*)y;
    for (size_t i = (size_t)blockIdx.x * blockDim.x + threadIdx.x; i < n4; i += stride) {
        const int o = (int)((i >> 12) & (O_DIM - 1));
        const float sc = ss[o];
        const float sh = ss[O_DIM + o];
        float4 v = y4[i];
        v.x = fmaxf(fmaf(v.x, sc, sh), 0.f);
        v.y = fmaxf(fmaf(v.y, sc, sh), 0.f);
        v.z = fmaxf(fmaf(v.z, sc, sh), 0.f);
        v.w = fmaxf(fmaf(v.w, sc, sh), 0.f);
        y4[i] = v;
    }
}

extern "C" void kernel_launch(void* const* d_in, const int* in_sizes, int n_in,
                              void* d_out, int out_size, void* d_ws, size_t ws_size,
                              hipStream_t stream) {
    const float* x       = (const float*)d_in[0];
    const int*   adj     = (const int*)  d_in[1];
    const float* W       = (const float*)d_in[2];
    const float* bias    = (const float*)d_in[3];
    const float* gamma   = (const float*)d_in[4];
    const float* beta_bn = (const float*)d_in[5];
    float* out = (float*)d_out;

    float*  stats = (float*)d_ws;                        // 256 f (fallback)
    float*  ss    = (float*)((char*)d_ws + 1024);        // 256 f
    ushort* Wtg   = (ushort*)((char*)d_ws + 4096);       // 32 KB
    ushort* xt    = (ushort*)((char*)d_ws + 65536);      // 64 MB bf16
    float*  part  = (float*)((char*)d_ws + 65536 + (size_t)B_DIM * F_DIM * C_DIM * 2);
    const size_t need = 65536 + (size_t)B_DIM * F_DIM * C_DIM * 2
                      + (size_t)2 * O_DIM * NBLK * sizeof(float);   // ~72 MB

    if (ws_size >= need) {
        k_transpose<<<dim3(F_DIM / 64, B_DIM), 256, 0, stream>>>(x, xt, W, Wtg);
        k_compute_t<0><<<dim3(F_DIM / 64, B_DIM), 256, 0, stream>>>(xt, adj, Wtg, bias, nullptr, nullptr, part);
        k_reduce_finalize<<<O_DIM, 256, 0, stream>>>(part, gamma, beta_bn, ss);
        k_compute_t<1><<<dim3(F_DIM / 64, B_DIM), 256, 0, stream>>>(xt, adj, Wtg, bias, ss, out, nullptr);
    } else {
        hipMemsetAsync(stats, 0, 2 * O_DIM * sizeof(float), stream);
        k_compute_slow<<<dim3(F_DIM / 256, B_DIM), 256, 0, stream>>>(x, adj, W, bias, out);
        k_stats<<<dim3(O_DIM, B_DIM), 256, 0, stream>>>(out, stats);
        k_finalize<<<1, 128, 0, stream>>>(stats, gamma, beta_bn, ss);
        k_norm<<<2048, 256, 0, stream>>>(out, ss);
    }
}